// Round 6
// baseline (236.789 us; speedup 1.0000x reference)
//
#include <hip/hip_runtime.h>

// Elementwise clamp: out = min(max(x, lo), hi)
// x: 33,554,432 fp32 (4194304 x 8). 128 MiB read + 128 MiB write.
//
// R6: software-pipelined rotation, load-BEFORE-store each iteration.
//  - R2's loop: loads(k+1) issued AFTER stores(k) -> in-order vmcnt
//    retirement forced every load-wait to drain prior stores (85 us).
//  - R4/R5 one-burst waves: no store->load gating but every wave pays a
//    cold latency ramp + store drain at s_endpgm; no steady state (78.5).
//  - R6: per iter, issue 4 loads of group g+1, THEN store group g. Loads
//    are OLDER than the stores in the vmcnt FIFO, so waiting for them is
//    a counted vmcnt that skips the stores. sched_barrier(0) pins the
//    load-block / store-block order so -O3 can't sink loads below stores.
//  - 1024 blocks x 256 threads, ILP=4 float4/group -> 8 groups/thread:
//    real steady state, fill-like long-running waves, 16 waves/CU.

typedef float f32x4 __attribute__((ext_vector_type(4)));

#define BLOCK 256
#define ILP 4

__device__ __forceinline__ f32x4 clamp4(f32x4 v, float lo, float hi) {
    v.x = fminf(fmaxf(v.x, lo), hi);
    v.y = fminf(fmaxf(v.y, lo), hi);
    v.z = fminf(fmaxf(v.z, lo), hi);
    v.w = fminf(fmaxf(v.w, lo), hi);
    return v;
}

__global__ void __launch_bounds__(BLOCK) clamp_kernel(
    const f32x4* __restrict__ x,
    const float* __restrict__ cp,
    f32x4* __restrict__ out,
    int n4)
{
    const float lo = cp[0];
    const float hi = cp[1];

    const int nthreads = gridDim.x * BLOCK;        // element stride within a group
    const int big = nthreads * ILP;                // elements per group (all threads)
    const int tid = blockIdx.x * BLOCK + threadIdx.x;
    const int ngroups = n4 / big;                  // 8 at the target shape

    if (ngroups > 0) {
        int i = tid;
        f32x4 cur[ILP];
        // Prologue: load group 0.
#pragma unroll
        for (int k = 0; k < ILP; ++k)
            cur[k] = x[i + k * nthreads];

        for (int g = 1; g < ngroups; ++g) {
            const int inext = i + big;
            f32x4 nxt[ILP];
            // Issue next group's loads FIRST (older than the stores below
            // in the vmcnt FIFO -> counted wait skips the stores).
#pragma unroll
            for (int k = 0; k < ILP; ++k)
                nxt[k] = x[inext + k * nthreads];
            __builtin_amdgcn_sched_barrier(0);     // pin: loads stay above stores
#pragma unroll
            for (int k = 0; k < ILP; ++k)
                out[i + k * nthreads] = clamp4(cur[k], lo, hi);
#pragma unroll
            for (int k = 0; k < ILP; ++k)
                cur[k] = nxt[k];
            i = inext;
        }
        // Epilogue: store last group.
#pragma unroll
        for (int k = 0; k < ILP; ++k)
            out[i + k * nthreads] = clamp4(cur[k], lo, hi);
    }

    // Generic tail (empty at the exact 4194304x8 shape).
    for (int idx = ngroups * big + tid; idx < n4; idx += nthreads)
        out[idx] = clamp4(x[idx], lo, hi);
}

extern "C" void kernel_launch(void* const* d_in, const int* in_sizes, int n_in,
                              void* d_out, int out_size, void* d_ws, size_t ws_size,
                              hipStream_t stream)
{
    const f32x4* x = (const f32x4*)d_in[0];
    const float* cp = (const float*)d_in[1];
    f32x4* out = (f32x4*)d_out;

    const int n = in_sizes[0];          // 33,554,432 fp32 elements
    const int n4 = n / 4;               // 8,388,608 float4s (exact)

    int grid = 1024;                    // 4 blocks/CU, long-running waves
    const int needed = (n4 + BLOCK - 1) / BLOCK;
    if (grid > needed) grid = needed;
    if (grid < 1) grid = 1;

    clamp_kernel<<<grid, BLOCK, 0, stream>>>(x, cp, out, n4);
}

// Round 7
// 218.581 us; speedup vs baseline: 1.0833x; 1.0833x over previous
//
#include <hip/hip_runtime.h>

// Elementwise clamp: out = min(max(x, lo), hi)
// x: 33,554,432 fp32 (4194304 x 8). 128 MiB read + 128 MiB write.
//
// R7 = R0's structure (all-time best total, 222.8 us) + NONTEMPORAL on
// both streams. Last untested mechanism-backed cell:
//  - nt-LOADS carried the only positive flavor signal in the trajectory:
//    R1 vs R2 (identical loop, only nt differs) = -11 us; R4 vs R5 showed
//    nt-STORES neutral => the -11 was the loads.
//  - Mechanism: nt bypasses L2/L3 allocation; the read stream stops
//    evicting/thrashing against fill-resident lines. m13's 6.3 TB/s
//    ceiling was measured on a clean cache; this harness's never is.
//  - Structure-insensitivity is established (one-shot / loop / burst /
//    pipeline all 78-85 us), so keep the simplest max-TLP shape:
//    one float4 per thread, 32768 blocks x 256.

typedef float f32x4 __attribute__((ext_vector_type(4)));

__device__ __forceinline__ f32x4 clamp4(f32x4 v, float lo, float hi) {
    // fminf(fmaxf(..)) -> v_med3_f32 clamp idiom
    v.x = fminf(fmaxf(v.x, lo), hi);
    v.y = fminf(fmaxf(v.y, lo), hi);
    v.z = fminf(fmaxf(v.z, lo), hi);
    v.w = fminf(fmaxf(v.w, lo), hi);
    return v;
}

__global__ void __launch_bounds__(256) clamp_kernel(
    const f32x4* __restrict__ x,
    const float* __restrict__ cp,
    f32x4* __restrict__ out,
    int n4)
{
    const float lo = cp[0];
    const float hi = cp[1];
    const int i = blockIdx.x * blockDim.x + threadIdx.x;
    if (i < n4) {
        f32x4 v = __builtin_nontemporal_load(&x[i]);
        __builtin_nontemporal_store(clamp4(v, lo, hi), &out[i]);
    }
}

extern "C" void kernel_launch(void* const* d_in, const int* in_sizes, int n_in,
                              void* d_out, int out_size, void* d_ws, size_t ws_size,
                              hipStream_t stream)
{
    const f32x4* x = (const f32x4*)d_in[0];
    const float* cp = (const float*)d_in[1];
    f32x4* out = (f32x4*)d_out;

    const int n = in_sizes[0];          // 33,554,432 fp32 elements
    const int n4 = n / 4;               // 8,388,608 float4s (exact)

    const int block = 256;
    const int grid = (n4 + block - 1) / block;   // 32,768 blocks

    clamp_kernel<<<grid, block, 0, stream>>>(x, cp, out, n4);
}